// Round 9
// baseline (650.472 us; speedup 1.0000x reference)
//
#include <hip/hip_runtime.h>
#include <hip/hip_bf16.h>
#include <float.h>

// EdgeConv (fp32 I/O):
//   out[b,o,n] = P[b,n,o] + max_{j<20} Q[b, idx[b,n,j], o]
//   P = (W1-W2)^T x + b ; Q = W2^T x
//   knn: top-20 smallest of score[m] = sq[m] - 2*x_n.x_m  (m != n)
// Round 9: round 8 with the slice-scan bug fixed (32 chunks/slice, not 16).
// m-split x4 (16 waves/CU) + compaction to global scratch (zero LDS in knn).
//   pass A: MFMA scores, per-lane min2 -> tau = 20th smallest of 64 minima
//   pass B: recompute, compact survivors (<= tau) to gbuf (CAP 48)
//   final: bitonic-sort survivors/row/slice, top-20 written in-place
//   merge: 4-way sorted merge -> idx. ws ~71 MiB.

#define BB 8
#define FF 64
#define NN 4096
#define KK 20
#define CAP 48
#define SS 4

typedef unsigned short ushort_t;
typedef unsigned long long u64;
typedef __attribute__((ext_vector_type(8))) short short8;
typedef __attribute__((ext_vector_type(16))) float float16;

// plane flat index (shorts): [b][n>>5][k>>3][n&31][k&7]
__device__ __forceinline__ size_t plidx(int b, int n, int k) {
  return ((size_t)b * 128 + (n >> 5)) * 2048 + (size_t)(k >> 3) * 256 + (size_t)(n & 31) * 8 + (k & 7);
}

// ---------------- prep: sq, Q, bf16x3 planes (fragment-tiled) ----------------
__global__ void __launch_bounds__(256) prep_kernel(
    const float* __restrict__ x, const float* __restrict__ W,
    float* __restrict__ sq, float* __restrict__ Q,
    ushort_t* __restrict__ ph, ushort_t* __restrict__ pm, ushort_t* __restrict__ pl)
{
  __shared__ float xs[64][65];
  __shared__ float w2[64][65];
  int t = threadIdx.x;
  int b = blockIdx.x >> 6;
  int n0 = (blockIdx.x & 63) << 6;
  const float* xb = x + (size_t)b * FF * NN;

  int nl = t & 63, fq = t >> 6;
  #pragma unroll
  for (int i = 0; i < 16; ++i) {
    int f = fq + i * 4;
    xs[f][nl] = xb[(size_t)f * NN + n0 + nl];
  }
  #pragma unroll
  for (int i = 0; i < 16; ++i) {
    int id = i * 256 + t;            // 0..4095
    int o = id >> 6, f = id & 63;
    w2[o][f] = W[o * 128 + 64 + f];  // W2
  }
  __syncthreads();

  if (t < 64) {
    float s = 0.f;
    #pragma unroll
    for (int f = 0; f < FF; ++f) { float v = xs[f][t]; s += v * v; }
    sq[b * NN + n0 + t] = s;
  }
  int o = t & 63, g = t >> 6;
  for (int i = 0; i < 16; ++i) {
    int r = g + i * 4;
    int n = n0 + r;
    float acc = 0.f;
    #pragma unroll
    for (int f = 0; f < FF; ++f) acc += w2[o][f] * xs[f][r];
    Q[((size_t)b * NN + n) * FF + o] = acc;

    float v = xs[o][r];
    __hip_bfloat16 hb = __float2bfloat16(v);
    float vh = __bfloat162float(hb);
    float r1 = v - vh;
    __hip_bfloat16 mb = __float2bfloat16(r1);
    float vm = __bfloat162float(mb);
    __hip_bfloat16 lb = __float2bfloat16(r1 - vm);
    size_t pb = plidx(b, n, o);
    ph[pb] = __bfloat16_as_ushort(hb);
    pm[pb] = __bfloat16_as_ushort(mb);
    pl[pb] = __bfloat16_as_ushort(lb);
  }
}

// identical 24-MFMA score chunk (bitwise same in both passes)
__device__ __forceinline__ void score_chunk(
    const ushort_t* __restrict__ ph, const ushort_t* __restrict__ pm,
    const ushort_t* __restrict__ pl, size_t cbase,
    const short8* Ah, const short8* Am, const short8* Al, float16& acc)
{
  short8 B0[4];
  #pragma unroll
  for (int s = 0; s < 4; ++s) B0[s] = *(const short8*)(ph + cbase + s * 512);
  #pragma unroll
  for (int s = 0; s < 4; ++s) acc = __builtin_amdgcn_mfma_f32_32x32x16_bf16(Ah[s], B0[s], acc, 0, 0, 0);
  #pragma unroll
  for (int s = 0; s < 4; ++s) acc = __builtin_amdgcn_mfma_f32_32x32x16_bf16(Am[s], B0[s], acc, 0, 0, 0);
  #pragma unroll
  for (int s = 0; s < 4; ++s) acc = __builtin_amdgcn_mfma_f32_32x32x16_bf16(Al[s], B0[s], acc, 0, 0, 0);
  #pragma unroll
  for (int s = 0; s < 4; ++s) B0[s] = *(const short8*)(pm + cbase + s * 512);
  #pragma unroll
  for (int s = 0; s < 4; ++s) acc = __builtin_amdgcn_mfma_f32_32x32x16_bf16(Ah[s], B0[s], acc, 0, 0, 0);
  #pragma unroll
  for (int s = 0; s < 4; ++s) acc = __builtin_amdgcn_mfma_f32_32x32x16_bf16(Am[s], B0[s], acc, 0, 0, 0);
  #pragma unroll
  for (int s = 0; s < 4; ++s) B0[s] = *(const short8*)(pl + cbase + s * 512);
  #pragma unroll
  for (int s = 0; s < 4; ++s) acc = __builtin_amdgcn_mfma_f32_32x32x16_bf16(Ah[s], B0[s], acc, 0, 0, 0);
}

// ascending bitonic sort of 64 floats as elements (2l, 2l+1) across 32 lanes
__device__ __forceinline__ void bitonic64f(float& v0, float& v1, int l31)
{
  #pragma unroll
  for (int k = 2; k <= 64; k <<= 1) {
    #pragma unroll
    for (int j = k >> 1; j >= 1; j >>= 1) {
      bool dirup = ((2 * l31) & k) == 0;
      if (j >= 2) {
        int lj = j >> 1;
        float p0 = __shfl_xor(v0, lj, 32);
        float p1 = __shfl_xor(v1, lj, 32);
        bool lower = (l31 & lj) == 0;
        bool keepmin = (dirup == lower);
        v0 = keepmin ? fminf(v0, p0) : fmaxf(v0, p0);
        v1 = keepmin ? fminf(v1, p1) : fmaxf(v1, p1);
      } else {
        float lo = fminf(v0, v1), hi = fmaxf(v0, v1);
        v0 = dirup ? lo : hi;
        v1 = dirup ? hi : lo;
      }
    }
  }
}

// same network on u64 keys
__device__ __forceinline__ void bitonic64k(u64& v0, u64& v1, int l31)
{
  #pragma unroll
  for (int k = 2; k <= 64; k <<= 1) {
    #pragma unroll
    for (int j = k >> 1; j >= 1; j >>= 1) {
      bool dirup = ((2 * l31) & k) == 0;
      if (j >= 2) {
        int lj = j >> 1;
        u64 p0 = __shfl_xor(v0, lj, 32);
        u64 p1 = __shfl_xor(v1, lj, 32);
        bool lower = (l31 & lj) == 0;
        bool keepmin = (dirup == lower);
        u64 a0 = v0 < p0 ? v0 : p0, b0 = v0 < p0 ? p0 : v0;
        u64 a1 = v1 < p1 ? v1 : p1, b1 = v1 < p1 ? p1 : v1;
        v0 = keepmin ? a0 : b0;
        v1 = keepmin ? a1 : b1;
      } else {
        u64 lo = v0 < v1 ? v0 : v1, hi = v0 < v1 ? v1 : v0;
        v0 = dirup ? lo : hi;
        v1 = dirup ? hi : lo;
      }
    }
  }
}

// ---------------- knn: two-pass threshold filter, slice = 1024 cols = 32 chunks ----------------
__global__ void __launch_bounds__(256, 4) knn_kernel(
    const ushort_t* __restrict__ ph, const ushort_t* __restrict__ pm,
    const ushort_t* __restrict__ pl, const float* __restrict__ sq,
    u64* __restrict__ gbuf)
{
  const int t = threadIdx.x;
  const int lane = t & 63;
  const int l31 = lane & 31;
  const int hf = lane >> 5;
  const int wv = t >> 6;
  const int blk = blockIdx.x;
  const int slice = blk & 3;
  const int g = (blk >> 2) & 31;
  const int b = blk >> 7;
  const int n0 = (g * 4 + wv) * 32;

  const float* __restrict__ sqb = sq + (size_t)b * NN;

  // resident A fragments: row = n0 + l31, k = 16*s + 8*hf + e
  short8 Ah[4], Am[4], Al[4];
  {
    size_t abase = ((size_t)b * 128 + (n0 >> 5)) * 2048 + (size_t)l31 * 8 + (size_t)hf * 256;
    #pragma unroll
    for (int s = 0; s < 4; ++s) {
      Ah[s] = *(const short8*)(ph + abase + s * 512);
      Am[s] = *(const short8*)(pm + abase + s * 512);
      Al[s] = *(const short8*)(pl + abase + s * 512);
    }
  }

  // -------- pass A: per-lane min2 per row over 32 chunks --------
  float m1[16], m2[16];
  #pragma unroll
  for (int r = 0; r < 16; ++r) { m1[r] = FLT_MAX; m2[r] = FLT_MAX; }

  for (int mc = 0; mc < 32; ++mc) {
    const int m0 = slice * 1024 + mc * 32;
    size_t cbase = ((size_t)b * 128 + (m0 >> 5)) * 2048 + (size_t)l31 * 8 + (size_t)hf * 256;
    float16 acc;
    #pragma unroll
    for (int q = 0; q < 16; ++q) acc[q] = 0.f;
    score_chunk(ph, pm, pl, cbase, Ah, Am, Al, acc);
    float sqv = sqb[m0 + l31];
    #pragma unroll
    for (int r = 0; r < 16; ++r) {
      float cand = __builtin_fmaf(-2.f, acc[r], sqv);
      int nrow = n0 + (r & 3) + 8 * (r >> 2) + 4 * hf;
      if (m0 + l31 == nrow) cand = FLT_MAX;       // self-exclusion
      m2[r] = fminf(m2[r], fmaxf(cand, m1[r]));
      m1[r] = fminf(m1[r], cand);
    }
  }

  // tau_r = 20th smallest (0-based 19) of the 64 per-lane minima
  float tau[16];
  #pragma unroll
  for (int r = 0; r < 16; ++r) {
    float v0 = m1[r], v1 = m2[r];
    bitonic64f(v0, v1, l31);
    tau[r] = __shfl(v1, 9, 32);                   // element 19 = lane 9, reg 1
  }

  // -------- pass B: recompute, compact survivors to global scratch --------
  int cnt[16];
  #pragma unroll
  for (int r = 0; r < 16; ++r) cnt[r] = 0;

  for (int mc = 0; mc < 32; ++mc) {
    const int m0 = slice * 1024 + mc * 32;
    size_t cbase = ((size_t)b * 128 + (m0 >> 5)) * 2048 + (size_t)l31 * 8 + (size_t)hf * 256;
    float16 acc;
    #pragma unroll
    for (int q = 0; q < 16; ++q) acc[q] = 0.f;
    score_chunk(ph, pm, pl, cbase, Ah, Am, Al, acc);
    float sqv = sqb[m0 + l31];
    #pragma unroll
    for (int r = 0; r < 16; ++r) {
      float cand = __builtin_fmaf(-2.f, acc[r], sqv);
      int nrow = n0 + (r & 3) + 8 * (r >> 2) + 4 * hf;
      bool ok = (m0 + l31 != nrow) && (cand <= tau[r]);
      unsigned long long bal = __ballot(ok);
      unsigned mh = hf ? (unsigned)(bal >> 32) : (unsigned)bal;
      if (mh) {
        int pre = __popc(mh & ((1u << l31) - 1u));
        int slot = cnt[r] + pre;
        if (ok && slot < CAP) {
          unsigned bits = __float_as_uint(cand);
          unsigned key32 = bits ^ ((bits >> 31) ? 0xFFFFFFFFu : 0x80000000u);
          size_t rs = ((size_t)(b * NN + nrow) * SS + slice) * CAP;
          gbuf[rs + slot] = ((u64)key32 << 32) | (unsigned)(m0 + l31);
        }
        cnt[r] += __popc(mh);
      }
    }
  }

  // -------- final: sort survivors per row/slice, write top-20 in-place --------
  #pragma unroll
  for (int r = 0; r < 16; ++r) {
    int c = cnt[r] < CAP ? cnt[r] : CAP;
    int nrow = n0 + (r & 3) + 8 * (r >> 2) + 4 * hf;
    size_t rs = ((size_t)(b * NN + nrow) * SS + slice) * CAP;
    u64 k0 = (2 * l31     < c) ? gbuf[rs + 2 * l31]     : ~0ull;
    u64 k1 = (2 * l31 + 1 < c) ? gbuf[rs + 2 * l31 + 1] : ~0ull;
    bitonic64k(k0, k1, l31);
    u64 a = __shfl(k0, l31 >> 1, 32);
    u64 b2 = __shfl(k1, l31 >> 1, 32);
    u64 kv = (l31 & 1) ? b2 : a;                  // element l31 of sorted order
    if (l31 < KK) gbuf[rs + l31] = kv;
  }
}

// ---------------- merge four sorted 20-key lists per row ----------------
__global__ void __launch_bounds__(256) merge_kernel(
    const u64* __restrict__ gbuf, int* __restrict__ idxOut)
{
  int row = blockIdx.x * 256 + threadIdx.x;   // 0..32767
  if (row >= BB * NN) return;
  u64 h[SS]; int p[SS];
  #pragma unroll
  for (int s = 0; s < SS; ++s) {
    p[s] = 0;
    h[s] = gbuf[((size_t)row * SS + s) * CAP];
  }
  int* op = idxOut + (size_t)row * KK;
  #pragma unroll
  for (int q = 0; q < KK; ++q) {
    int bs = 0;
    u64 bv = h[0];
    #pragma unroll
    for (int s = 1; s < SS; ++s) { if (h[s] < bv) { bv = h[s]; bs = s; } }
    op[q] = (int)(unsigned)(bv & 0xFFFFFFFFull);
    p[bs]++;
    h[bs] = (p[bs] < KK) ? gbuf[((size_t)row * SS + bs) * CAP + p[bs]] : ~0ull;
  }
}

// ---------------- gather: out[b,o,n] = P + max_j Q[nbr_j] ----------------
__global__ void __launch_bounds__(256) gather_kernel(
    const float* __restrict__ x, const float* __restrict__ W,
    const float* __restrict__ bias,
    const float* __restrict__ Q, const int* __restrict__ idxIn,
    float* __restrict__ out)
{
  __shared__ float xs[64][65];
  __shared__ float wp[64][65];
  __shared__ float ot[64][65];
  __shared__ float bs[64];
  int t = threadIdx.x;
  int b = blockIdx.x >> 6;
  int n0 = (blockIdx.x & 63) << 6;
  const float* xb = x + (size_t)b * FF * NN;

  int nl0 = t & 63, fq = t >> 6;
  #pragma unroll
  for (int i = 0; i < 16; ++i) {
    int f = fq + i * 4;
    xs[f][nl0] = xb[(size_t)f * NN + n0 + nl0];
  }
  #pragma unroll
  for (int i = 0; i < 16; ++i) {
    int id = i * 256 + t;            // 0..4095
    int o = id >> 6, f = id & 63;
    wp[o][f] = W[o * 128 + f] - W[o * 128 + 64 + f];   // W1 - W2
  }
  if (t < 64) bs[t] = bias[t];
  __syncthreads();

  int o = t & 63, g = t >> 6;
  for (int i = 0; i < 16; ++i) {
    int nl = g + i * 4;
    int n = n0 + nl;
    float p = bs[o];
    #pragma unroll
    for (int f = 0; f < FF; ++f) p += wp[o][f] * xs[f][nl];
    const int* ip = idxIn + ((size_t)b * NN + n) * KK;
    float m = -FLT_MAX;
    #pragma unroll
    for (int j = 0; j < KK; ++j) {
      int nb = ip[j];                                   // wave-uniform
      m = fmaxf(m, Q[((size_t)b * NN + nb) * FF + o]);  // 256B coalesced
    }
    ot[nl][o] = p + m;
  }
  __syncthreads();
  for (int i = 0; i < 16; ++i) {
    int o2 = g + i * 4;
    int nl = t & 63;
    out[((size_t)b * FF + o2) * NN + n0 + nl] = ot[nl][o2];
  }
}

extern "C" void kernel_launch(void* const* d_in, const int* in_sizes, int n_in,
                              void* d_out, int out_size, void* d_ws, size_t ws_size,
                              hipStream_t stream)
{
  const float* x    = (const float*)d_in[0];
  const float* W    = (const float*)d_in[1];
  const float* bias = (const float*)d_in[2];
  float* out = (float*)d_out;

  int*   idxb = (int*)d_ws;                               // 8*4096*20
  float* sq   = (float*)(idxb + (size_t)BB * NN * KK);    // 8*4096
  float* Q    = sq + (size_t)BB * NN;                     // 8*4096*64
  ushort_t* ph = (ushort_t*)(Q + (size_t)BB * NN * FF);   // 8*4096*64 each
  ushort_t* pm = ph + (size_t)BB * NN * FF;
  ushort_t* pl = pm + (size_t)BB * NN * FF;
  u64*   gbuf = (u64*)(pl + (size_t)BB * NN * FF);        // 8*4096*4*48

  prep_kernel<<<BB * (NN / 64), 256, 0, stream>>>(x, W, sq, Q, ph, pm, pl);
  knn_kernel<<<BB * 32 * SS, 256, 0, stream>>>(ph, pm, pl, sq, gbuf);
  merge_kernel<<<(BB * NN + 255) / 256, 256, 0, stream>>>(gbuf, idxb);
  gather_kernel<<<BB * (NN / 64), 256, 0, stream>>>(x, W, bias, Q, idxb, out);
}

// Round 10
// 472.180 us; speedup vs baseline: 1.3776x; 1.3776x over previous
//
#include <hip/hip_runtime.h>
#include <hip/hip_bf16.h>
#include <float.h>

// EdgeConv (fp32 I/O):
//   out[b,o,n] = P[b,n,o] + max_{j<20} Q[b, idx[b,n,j], o]
//   P = (W1-W2)^T x + b ; Q = W2^T x
//   knn: top-20 smallest of score[m] = sq[m] - 2*x_n.x_m  (m != n)
// Round 10: LDS compaction (round 7, on-chip, no HBM write-amp) + 4-slice grid
// (round 9, 4 blocks/CU occupancy). CAP 40 -> 40960B LDS = exactly 4 blocks/CU.
//   pass A: MFMA scores, per-lane min2 -> tau = 20th smallest of 64-pool
//   pass B: recompute, compact survivors (<= tau) into LDS buf
//   final: bitonic sort per row/slice -> sorted top-20 keys to keys2 (coalesced)
//   merge: 4-way sorted merge -> idx

#define BB 8
#define FF 64
#define NN 4096
#define KK 20
#define CAP 40
#define SS 4

typedef unsigned short ushort_t;
typedef unsigned long long u64;
typedef __attribute__((ext_vector_type(8))) short short8;
typedef __attribute__((ext_vector_type(16))) float float16;

// plane flat index (shorts): [b][n>>5][k>>3][n&31][k&7]
__device__ __forceinline__ size_t plidx(int b, int n, int k) {
  return ((size_t)b * 128 + (n >> 5)) * 2048 + (size_t)(k >> 3) * 256 + (size_t)(n & 31) * 8 + (k & 7);
}

// ---------------- prep: sq, Q, bf16x3 planes (fragment-tiled) ----------------
__global__ void __launch_bounds__(256) prep_kernel(
    const float* __restrict__ x, const float* __restrict__ W,
    float* __restrict__ sq, float* __restrict__ Q,
    ushort_t* __restrict__ ph, ushort_t* __restrict__ pm, ushort_t* __restrict__ pl)
{
  __shared__ float xs[64][65];
  __shared__ float w2[64][65];
  int t = threadIdx.x;
  int b = blockIdx.x >> 6;
  int n0 = (blockIdx.x & 63) << 6;
  const float* xb = x + (size_t)b * FF * NN;

  int nl = t & 63, fq = t >> 6;
  #pragma unroll
  for (int i = 0; i < 16; ++i) {
    int f = fq + i * 4;
    xs[f][nl] = xb[(size_t)f * NN + n0 + nl];
  }
  #pragma unroll
  for (int i = 0; i < 16; ++i) {
    int id = i * 256 + t;            // 0..4095
    int o = id >> 6, f = id & 63;
    w2[o][f] = W[o * 128 + 64 + f];  // W2
  }
  __syncthreads();

  if (t < 64) {
    float s = 0.f;
    #pragma unroll
    for (int f = 0; f < FF; ++f) { float v = xs[f][t]; s += v * v; }
    sq[b * NN + n0 + t] = s;
  }
  int o = t & 63, g = t >> 6;
  for (int i = 0; i < 16; ++i) {
    int r = g + i * 4;
    int n = n0 + r;
    float acc = 0.f;
    #pragma unroll
    for (int f = 0; f < FF; ++f) acc += w2[o][f] * xs[f][r];
    Q[((size_t)b * NN + n) * FF + o] = acc;

    float v = xs[o][r];
    __hip_bfloat16 hb = __float2bfloat16(v);
    float vh = __bfloat162float(hb);
    float r1 = v - vh;
    __hip_bfloat16 mb = __float2bfloat16(r1);
    float vm = __bfloat162float(mb);
    __hip_bfloat16 lb = __float2bfloat16(r1 - vm);
    size_t pb = plidx(b, n, o);
    ph[pb] = __bfloat16_as_ushort(hb);
    pm[pb] = __bfloat16_as_ushort(mb);
    pl[pb] = __bfloat16_as_ushort(lb);
  }
}

// identical 24-MFMA score chunk (bitwise same in both passes)
__device__ __forceinline__ void score_chunk(
    const ushort_t* __restrict__ ph, const ushort_t* __restrict__ pm,
    const ushort_t* __restrict__ pl, size_t cbase,
    const short8* Ah, const short8* Am, const short8* Al, float16& acc)
{
  short8 B0[4];
  #pragma unroll
  for (int s = 0; s < 4; ++s) B0[s] = *(const short8*)(ph + cbase + s * 512);
  #pragma unroll
  for (int s = 0; s < 4; ++s) acc = __builtin_amdgcn_mfma_f32_32x32x16_bf16(Ah[s], B0[s], acc, 0, 0, 0);
  #pragma unroll
  for (int s = 0; s < 4; ++s) acc = __builtin_amdgcn_mfma_f32_32x32x16_bf16(Am[s], B0[s], acc, 0, 0, 0);
  #pragma unroll
  for (int s = 0; s < 4; ++s) acc = __builtin_amdgcn_mfma_f32_32x32x16_bf16(Al[s], B0[s], acc, 0, 0, 0);
  #pragma unroll
  for (int s = 0; s < 4; ++s) B0[s] = *(const short8*)(pm + cbase + s * 512);
  #pragma unroll
  for (int s = 0; s < 4; ++s) acc = __builtin_amdgcn_mfma_f32_32x32x16_bf16(Ah[s], B0[s], acc, 0, 0, 0);
  #pragma unroll
  for (int s = 0; s < 4; ++s) acc = __builtin_amdgcn_mfma_f32_32x32x16_bf16(Am[s], B0[s], acc, 0, 0, 0);
  #pragma unroll
  for (int s = 0; s < 4; ++s) B0[s] = *(const short8*)(pl + cbase + s * 512);
  #pragma unroll
  for (int s = 0; s < 4; ++s) acc = __builtin_amdgcn_mfma_f32_32x32x16_bf16(Ah[s], B0[s], acc, 0, 0, 0);
}

// ascending bitonic sort of 64 floats as elements (2l, 2l+1) across 32 lanes
__device__ __forceinline__ void bitonic64f(float& v0, float& v1, int l31)
{
  #pragma unroll
  for (int k = 2; k <= 64; k <<= 1) {
    #pragma unroll
    for (int j = k >> 1; j >= 1; j >>= 1) {
      bool dirup = ((2 * l31) & k) == 0;
      if (j >= 2) {
        int lj = j >> 1;
        float p0 = __shfl_xor(v0, lj, 32);
        float p1 = __shfl_xor(v1, lj, 32);
        bool lower = (l31 & lj) == 0;
        bool keepmin = (dirup == lower);
        v0 = keepmin ? fminf(v0, p0) : fmaxf(v0, p0);
        v1 = keepmin ? fminf(v1, p1) : fmaxf(v1, p1);
      } else {
        float lo = fminf(v0, v1), hi = fmaxf(v0, v1);
        v0 = dirup ? lo : hi;
        v1 = dirup ? hi : lo;
      }
    }
  }
}

// same network on u64 keys
__device__ __forceinline__ void bitonic64k(u64& v0, u64& v1, int l31)
{
  #pragma unroll
  for (int k = 2; k <= 64; k <<= 1) {
    #pragma unroll
    for (int j = k >> 1; j >= 1; j >>= 1) {
      bool dirup = ((2 * l31) & k) == 0;
      if (j >= 2) {
        int lj = j >> 1;
        u64 p0 = __shfl_xor(v0, lj, 32);
        u64 p1 = __shfl_xor(v1, lj, 32);
        bool lower = (l31 & lj) == 0;
        bool keepmin = (dirup == lower);
        u64 a0 = v0 < p0 ? v0 : p0, b0 = v0 < p0 ? p0 : v0;
        u64 a1 = v1 < p1 ? v1 : p1, b1 = v1 < p1 ? p1 : v1;
        v0 = keepmin ? a0 : b0;
        v1 = keepmin ? a1 : b1;
      } else {
        u64 lo = v0 < v1 ? v0 : v1, hi = v0 < v1 ? v1 : v0;
        v0 = dirup ? lo : hi;
        v1 = dirup ? hi : lo;
      }
    }
  }
}

// ---------------- knn: two-pass threshold filter, slice = 1024 cols = 32 chunks ----------------
__global__ void __launch_bounds__(256, 4) knn_kernel(
    const ushort_t* __restrict__ ph, const ushort_t* __restrict__ pm,
    const ushort_t* __restrict__ pl, const float* __restrict__ sq,
    u64* __restrict__ keys2)
{
  __shared__ u64 buf[4][32][CAP];   // 40960 B -> 4 blocks/CU

  const int t = threadIdx.x;
  const int lane = t & 63;
  const int l31 = lane & 31;
  const int hf = lane >> 5;
  const int wv = t >> 6;
  const int blk = blockIdx.x;
  const int slice = blk & 3;
  const int g = (blk >> 2) & 31;
  const int b = blk >> 7;
  const int n0 = (g * 4 + wv) * 32;

  const float* __restrict__ sqb = sq + (size_t)b * NN;

  // resident A fragments: row = n0 + l31, k = 16*s + 8*hf + e
  short8 Ah[4], Am[4], Al[4];
  {
    size_t abase = ((size_t)b * 128 + (n0 >> 5)) * 2048 + (size_t)l31 * 8 + (size_t)hf * 256;
    #pragma unroll
    for (int s = 0; s < 4; ++s) {
      Ah[s] = *(const short8*)(ph + abase + s * 512);
      Am[s] = *(const short8*)(pm + abase + s * 512);
      Al[s] = *(const short8*)(pl + abase + s * 512);
    }
  }

  // -------- pass A: per-lane min2 per row over 32 chunks --------
  float m1[16], m2[16];
  #pragma unroll
  for (int r = 0; r < 16; ++r) { m1[r] = FLT_MAX; m2[r] = FLT_MAX; }

  for (int mc = 0; mc < 32; ++mc) {
    const int m0 = slice * 1024 + mc * 32;
    size_t cbase = ((size_t)b * 128 + (m0 >> 5)) * 2048 + (size_t)l31 * 8 + (size_t)hf * 256;
    float16 acc;
    #pragma unroll
    for (int q = 0; q < 16; ++q) acc[q] = 0.f;
    score_chunk(ph, pm, pl, cbase, Ah, Am, Al, acc);
    float sqv = sqb[m0 + l31];
    #pragma unroll
    for (int r = 0; r < 16; ++r) {
      float cand = __builtin_fmaf(-2.f, acc[r], sqv);
      int nrow = n0 + (r & 3) + 8 * (r >> 2) + 4 * hf;
      if (m0 + l31 == nrow) cand = FLT_MAX;       // self-exclusion
      m2[r] = fminf(m2[r], fmaxf(cand, m1[r]));
      m1[r] = fminf(m1[r], cand);
    }
  }

  // tau_r = 20th smallest (0-based 19) of the 64-pool of per-lane min2
  float tau[16];
  #pragma unroll
  for (int r = 0; r < 16; ++r) {
    float v0 = m1[r], v1 = m2[r];
    bitonic64f(v0, v1, l31);
    tau[r] = __shfl(v1, 9, 32);                   // element 19 = lane 9, reg 1
  }

  // -------- pass B: recompute, compact survivors into LDS --------
  int cnt[16];
  #pragma unroll
  for (int r = 0; r < 16; ++r) cnt[r] = 0;

  for (int mc = 0; mc < 32; ++mc) {
    const int m0 = slice * 1024 + mc * 32;
    size_t cbase = ((size_t)b * 128 + (m0 >> 5)) * 2048 + (size_t)l31 * 8 + (size_t)hf * 256;
    float16 acc;
    #pragma unroll
    for (int q = 0; q < 16; ++q) acc[q] = 0.f;
    score_chunk(ph, pm, pl, cbase, Ah, Am, Al, acc);
    float sqv = sqb[m0 + l31];
    #pragma unroll
    for (int r = 0; r < 16; ++r) {
      float cand = __builtin_fmaf(-2.f, acc[r], sqv);
      int nrow = n0 + (r & 3) + 8 * (r >> 2) + 4 * hf;
      bool ok = (m0 + l31 != nrow) && (cand <= tau[r]);
      unsigned long long bal = __ballot(ok);
      unsigned mh = hf ? (unsigned)(bal >> 32) : (unsigned)bal;
      if (mh) {
        int pre = __popc(mh & ((1u << l31) - 1u));
        int slot = cnt[r] + pre;
        if (ok && slot < CAP) {
          unsigned bits = __float_as_uint(cand);
          unsigned key32 = bits ^ ((bits >> 31) ? 0xFFFFFFFFu : 0x80000000u);
          buf[wv][r + 16 * hf][slot] = ((u64)key32 << 32) | (unsigned)(m0 + l31);
        }
        cnt[r] += __popc(mh);
      }
    }
  }

  // -------- final: sort survivors per row/slice, emit sorted top-20 --------
  #pragma unroll
  for (int r = 0; r < 16; ++r) {
    int c = cnt[r] < CAP ? cnt[r] : CAP;
    int rr = r + 16 * hf;
    u64 k0 = (2 * l31     < c) ? buf[wv][rr][2 * l31]     : ~0ull;
    u64 k1 = (2 * l31 + 1 < c) ? buf[wv][rr][2 * l31 + 1] : ~0ull;
    bitonic64k(k0, k1, l31);
    u64 a = __shfl(k0, l31 >> 1, 32);
    u64 b2 = __shfl(k1, l31 >> 1, 32);
    u64 kv = (l31 & 1) ? b2 : a;                  // element l31 of sorted order
    if (l31 < KK) {
      int nrow = n0 + (r & 3) + 8 * (r >> 2) + 4 * hf;
      size_t rowg = ((size_t)b * NN + nrow) * SS + slice;
      keys2[rowg * KK + l31] = kv;
    }
  }
}

// ---------------- merge four sorted 20-key lists per row ----------------
__global__ void __launch_bounds__(256) merge_kernel(
    const u64* __restrict__ keys2, int* __restrict__ idxOut)
{
  int row = blockIdx.x * 256 + threadIdx.x;   // 0..32767
  if (row >= BB * NN) return;
  u64 h[SS]; int p[SS];
  #pragma unroll
  for (int s = 0; s < SS; ++s) {
    p[s] = 0;
    h[s] = keys2[((size_t)row * SS + s) * KK];
  }
  int* op = idxOut + (size_t)row * KK;
  #pragma unroll
  for (int q = 0; q < KK; ++q) {
    int bs = 0;
    u64 bv = h[0];
    #pragma unroll
    for (int s = 1; s < SS; ++s) { if (h[s] < bv) { bv = h[s]; bs = s; } }
    op[q] = (int)(unsigned)(bv & 0xFFFFFFFFull);
    p[bs]++;
    h[bs] = (p[bs] < KK) ? keys2[((size_t)row * SS + bs) * KK + p[bs]] : ~0ull;
  }
}

// ---------------- gather: out[b,o,n] = P + max_j Q[nbr_j] ----------------
__global__ void __launch_bounds__(256) gather_kernel(
    const float* __restrict__ x, const float* __restrict__ W,
    const float* __restrict__ bias,
    const float* __restrict__ Q, const int* __restrict__ idxIn,
    float* __restrict__ out)
{
  __shared__ float xs[64][65];
  __shared__ float wp[64][65];
  __shared__ float ot[64][65];
  __shared__ float bs[64];
  int t = threadIdx.x;
  int b = blockIdx.x >> 6;
  int n0 = (blockIdx.x & 63) << 6;
  const float* xb = x + (size_t)b * FF * NN;

  int nl0 = t & 63, fq = t >> 6;
  #pragma unroll
  for (int i = 0; i < 16; ++i) {
    int f = fq + i * 4;
    xs[f][nl0] = xb[(size_t)f * NN + n0 + nl0];
  }
  #pragma unroll
  for (int i = 0; i < 16; ++i) {
    int id = i * 256 + t;            // 0..4095
    int o = id >> 6, f = id & 63;
    wp[o][f] = W[o * 128 + f] - W[o * 128 + 64 + f];   // W1 - W2
  }
  if (t < 64) bs[t] = bias[t];
  __syncthreads();

  int o = t & 63, g = t >> 6;
  for (int i = 0; i < 16; ++i) {
    int nl = g + i * 4;
    int n = n0 + nl;
    float p = bs[o];
    #pragma unroll
    for (int f = 0; f < FF; ++f) p += wp[o][f] * xs[f][nl];
    const int* ip = idxIn + ((size_t)b * NN + n) * KK;
    float m = -FLT_MAX;
    #pragma unroll
    for (int j = 0; j < KK; ++j) {
      int nb = ip[j];                                   // wave-uniform
      m = fmaxf(m, Q[((size_t)b * NN + nb) * FF + o]);  // 256B coalesced
    }
    ot[nl][o] = p + m;
  }
  __syncthreads();
  for (int i = 0; i < 16; ++i) {
    int o2 = g + i * 4;
    int nl = t & 63;
    out[((size_t)b * FF + o2) * NN + n0 + nl] = ot[nl][o2];
  }
}

extern "C" void kernel_launch(void* const* d_in, const int* in_sizes, int n_in,
                              void* d_out, int out_size, void* d_ws, size_t ws_size,
                              hipStream_t stream)
{
  const float* x    = (const float*)d_in[0];
  const float* W    = (const float*)d_in[1];
  const float* bias = (const float*)d_in[2];
  float* out = (float*)d_out;

  int*   idxb = (int*)d_ws;                               // 8*4096*20
  float* sq   = (float*)(idxb + (size_t)BB * NN * KK);    // 8*4096
  float* Q    = sq + (size_t)BB * NN;                     // 8*4096*64
  ushort_t* ph = (ushort_t*)(Q + (size_t)BB * NN * FF);   // 8*4096*64 each
  ushort_t* pm = ph + (size_t)BB * NN * FF;
  ushort_t* pl = pm + (size_t)BB * NN * FF;
  u64*   keys2 = (u64*)(pl + (size_t)BB * NN * FF);       // 8*4096*4*20

  prep_kernel<<<BB * (NN / 64), 256, 0, stream>>>(x, W, sq, Q, ph, pm, pl);
  knn_kernel<<<BB * 32 * SS, 256, 0, stream>>>(ph, pm, pl, sq, keys2);
  merge_kernel<<<(BB * NN + 255) / 256, 256, 0, stream>>>(keys2, idxb);
  gather_kernel<<<BB * (NN / 64), 256, 0, stream>>>(x, W, bias, Q, idxb, out);
}

// Round 11
// 420.740 us; speedup vs baseline: 1.5460x; 1.1223x over previous
//
#include <hip/hip_runtime.h>
#include <hip/hip_bf16.h>
#include <float.h>

// EdgeConv (fp32 I/O):
//   out[b,o,n] = P[b,n,o] + max_{j<20} Q[b, idx[b,n,j], o]
//   P = (W1-W2)^T x + b ; Q = W2^T x
//   knn: top-20 smallest of score[m] = sq[m] - 2*x_n.x_m  (m != n)
// Round 11: round 10 with the register spill fixed. LB(256,4) capped VGPR at 64
// while demand is ~130 -> m1/m2/tau/cnt spilled to scratch (the 67MB WRITE_SIZE
// and the occupancy-invariant 360us). LB(256,3) -> ~170 VGPR cap, no spill,
// 3 blocks/CU (LDS 48KB x 3 = 147KB). Algorithm identical.

#define BB 8
#define FF 64
#define NN 4096
#define KK 20
#define CAP 48
#define SS 4

typedef unsigned short ushort_t;
typedef unsigned long long u64;
typedef __attribute__((ext_vector_type(8))) short short8;
typedef __attribute__((ext_vector_type(16))) float float16;

// plane flat index (shorts): [b][n>>5][k>>3][n&31][k&7]
__device__ __forceinline__ size_t plidx(int b, int n, int k) {
  return ((size_t)b * 128 + (n >> 5)) * 2048 + (size_t)(k >> 3) * 256 + (size_t)(n & 31) * 8 + (k & 7);
}

// ---------------- prep: sq, Q, bf16x3 planes (fragment-tiled) ----------------
__global__ void __launch_bounds__(256) prep_kernel(
    const float* __restrict__ x, const float* __restrict__ W,
    float* __restrict__ sq, float* __restrict__ Q,
    ushort_t* __restrict__ ph, ushort_t* __restrict__ pm, ushort_t* __restrict__ pl)
{
  __shared__ float xs[64][65];
  __shared__ float w2[64][65];
  int t = threadIdx.x;
  int b = blockIdx.x >> 6;
  int n0 = (blockIdx.x & 63) << 6;
  const float* xb = x + (size_t)b * FF * NN;

  int nl = t & 63, fq = t >> 6;
  #pragma unroll
  for (int i = 0; i < 16; ++i) {
    int f = fq + i * 4;
    xs[f][nl] = xb[(size_t)f * NN + n0 + nl];
  }
  #pragma unroll
  for (int i = 0; i < 16; ++i) {
    int id = i * 256 + t;            // 0..4095
    int o = id >> 6, f = id & 63;
    w2[o][f] = W[o * 128 + 64 + f];  // W2
  }
  __syncthreads();

  if (t < 64) {
    float s = 0.f;
    #pragma unroll
    for (int f = 0; f < FF; ++f) { float v = xs[f][t]; s += v * v; }
    sq[b * NN + n0 + t] = s;
  }
  int o = t & 63, g = t >> 6;
  for (int i = 0; i < 16; ++i) {
    int r = g + i * 4;
    int n = n0 + r;
    float acc = 0.f;
    #pragma unroll
    for (int f = 0; f < FF; ++f) acc += w2[o][f] * xs[f][r];
    Q[((size_t)b * NN + n) * FF + o] = acc;

    float v = xs[o][r];
    __hip_bfloat16 hb = __float2bfloat16(v);
    float vh = __bfloat162float(hb);
    float r1 = v - vh;
    __hip_bfloat16 mb = __float2bfloat16(r1);
    float vm = __bfloat162float(mb);
    __hip_bfloat16 lb = __float2bfloat16(r1 - vm);
    size_t pb = plidx(b, n, o);
    ph[pb] = __bfloat16_as_ushort(hb);
    pm[pb] = __bfloat16_as_ushort(mb);
    pl[pb] = __bfloat16_as_ushort(lb);
  }
}

// identical 24-MFMA score chunk (bitwise same in both passes)
__device__ __forceinline__ void score_chunk(
    const ushort_t* __restrict__ ph, const ushort_t* __restrict__ pm,
    const ushort_t* __restrict__ pl, size_t cbase,
    const short8* Ah, const short8* Am, const short8* Al, float16& acc)
{
  short8 B0[4];
  #pragma unroll
  for (int s = 0; s < 4; ++s) B0[s] = *(const short8*)(ph + cbase + s * 512);
  #pragma unroll
  for (int s = 0; s < 4; ++s) acc = __builtin_amdgcn_mfma_f32_32x32x16_bf16(Ah[s], B0[s], acc, 0, 0, 0);
  #pragma unroll
  for (int s = 0; s < 4; ++s) acc = __builtin_amdgcn_mfma_f32_32x32x16_bf16(Am[s], B0[s], acc, 0, 0, 0);
  #pragma unroll
  for (int s = 0; s < 4; ++s) acc = __builtin_amdgcn_mfma_f32_32x32x16_bf16(Al[s], B0[s], acc, 0, 0, 0);
  #pragma unroll
  for (int s = 0; s < 4; ++s) B0[s] = *(const short8*)(pm + cbase + s * 512);
  #pragma unroll
  for (int s = 0; s < 4; ++s) acc = __builtin_amdgcn_mfma_f32_32x32x16_bf16(Ah[s], B0[s], acc, 0, 0, 0);
  #pragma unroll
  for (int s = 0; s < 4; ++s) acc = __builtin_amdgcn_mfma_f32_32x32x16_bf16(Am[s], B0[s], acc, 0, 0, 0);
  #pragma unroll
  for (int s = 0; s < 4; ++s) B0[s] = *(const short8*)(pl + cbase + s * 512);
  #pragma unroll
  for (int s = 0; s < 4; ++s) acc = __builtin_amdgcn_mfma_f32_32x32x16_bf16(Ah[s], B0[s], acc, 0, 0, 0);
}

// ascending bitonic sort of 64 floats as elements (2l, 2l+1) across 32 lanes
__device__ __forceinline__ void bitonic64f(float& v0, float& v1, int l31)
{
  #pragma unroll
  for (int k = 2; k <= 64; k <<= 1) {
    #pragma unroll
    for (int j = k >> 1; j >= 1; j >>= 1) {
      bool dirup = ((2 * l31) & k) == 0;
      if (j >= 2) {
        int lj = j >> 1;
        float p0 = __shfl_xor(v0, lj, 32);
        float p1 = __shfl_xor(v1, lj, 32);
        bool lower = (l31 & lj) == 0;
        bool keepmin = (dirup == lower);
        v0 = keepmin ? fminf(v0, p0) : fmaxf(v0, p0);
        v1 = keepmin ? fminf(v1, p1) : fmaxf(v1, p1);
      } else {
        float lo = fminf(v0, v1), hi = fmaxf(v0, v1);
        v0 = dirup ? lo : hi;
        v1 = dirup ? hi : lo;
      }
    }
  }
}

// same network on u64 keys
__device__ __forceinline__ void bitonic64k(u64& v0, u64& v1, int l31)
{
  #pragma unroll
  for (int k = 2; k <= 64; k <<= 1) {
    #pragma unroll
    for (int j = k >> 1; j >= 1; j >>= 1) {
      bool dirup = ((2 * l31) & k) == 0;
      if (j >= 2) {
        int lj = j >> 1;
        u64 p0 = __shfl_xor(v0, lj, 32);
        u64 p1 = __shfl_xor(v1, lj, 32);
        bool lower = (l31 & lj) == 0;
        bool keepmin = (dirup == lower);
        u64 a0 = v0 < p0 ? v0 : p0, b0 = v0 < p0 ? p0 : v0;
        u64 a1 = v1 < p1 ? v1 : p1, b1 = v1 < p1 ? p1 : v1;
        v0 = keepmin ? a0 : b0;
        v1 = keepmin ? a1 : b1;
      } else {
        u64 lo = v0 < v1 ? v0 : v1, hi = v0 < v1 ? v1 : v0;
        v0 = dirup ? lo : hi;
        v1 = dirup ? hi : lo;
      }
    }
  }
}

// ---------------- knn: two-pass threshold filter, slice = 1024 cols = 32 chunks ----------------
__global__ void __launch_bounds__(256, 3) knn_kernel(
    const ushort_t* __restrict__ ph, const ushort_t* __restrict__ pm,
    const ushort_t* __restrict__ pl, const float* __restrict__ sq,
    u64* __restrict__ keys2)
{
  __shared__ u64 buf[4][32][CAP];   // 49152 B -> 3 blocks/CU (147KB/160KB)

  const int t = threadIdx.x;
  const int lane = t & 63;
  const int l31 = lane & 31;
  const int hf = lane >> 5;
  const int wv = t >> 6;
  const int blk = blockIdx.x;
  const int slice = blk & 3;
  const int g = (blk >> 2) & 31;
  const int b = blk >> 7;
  const int n0 = (g * 4 + wv) * 32;

  const float* __restrict__ sqb = sq + (size_t)b * NN;

  // resident A fragments: row = n0 + l31, k = 16*s + 8*hf + e
  short8 Ah[4], Am[4], Al[4];
  {
    size_t abase = ((size_t)b * 128 + (n0 >> 5)) * 2048 + (size_t)l31 * 8 + (size_t)hf * 256;
    #pragma unroll
    for (int s = 0; s < 4; ++s) {
      Ah[s] = *(const short8*)(ph + abase + s * 512);
      Am[s] = *(const short8*)(pm + abase + s * 512);
      Al[s] = *(const short8*)(pl + abase + s * 512);
    }
  }

  // -------- pass A: per-lane min2 per row over 32 chunks --------
  float m1[16], m2[16];
  #pragma unroll
  for (int r = 0; r < 16; ++r) { m1[r] = FLT_MAX; m2[r] = FLT_MAX; }

  for (int mc = 0; mc < 32; ++mc) {
    const int m0 = slice * 1024 + mc * 32;
    size_t cbase = ((size_t)b * 128 + (m0 >> 5)) * 2048 + (size_t)l31 * 8 + (size_t)hf * 256;
    float16 acc;
    #pragma unroll
    for (int q = 0; q < 16; ++q) acc[q] = 0.f;
    score_chunk(ph, pm, pl, cbase, Ah, Am, Al, acc);
    float sqv = sqb[m0 + l31];
    #pragma unroll
    for (int r = 0; r < 16; ++r) {
      float cand = __builtin_fmaf(-2.f, acc[r], sqv);
      int nrow = n0 + (r & 3) + 8 * (r >> 2) + 4 * hf;
      if (m0 + l31 == nrow) cand = FLT_MAX;       // self-exclusion
      m2[r] = fminf(m2[r], fmaxf(cand, m1[r]));
      m1[r] = fminf(m1[r], cand);
    }
  }

  // tau_r = 20th smallest (0-based 19) of the 64-pool of per-lane min2
  float tau[16];
  #pragma unroll
  for (int r = 0; r < 16; ++r) {
    float v0 = m1[r], v1 = m2[r];
    bitonic64f(v0, v1, l31);
    tau[r] = __shfl(v1, 9, 32);                   // element 19 = lane 9, reg 1
  }

  // -------- pass B: recompute, compact survivors into LDS --------
  int cnt[16];
  #pragma unroll
  for (int r = 0; r < 16; ++r) cnt[r] = 0;

  for (int mc = 0; mc < 32; ++mc) {
    const int m0 = slice * 1024 + mc * 32;
    size_t cbase = ((size_t)b * 128 + (m0 >> 5)) * 2048 + (size_t)l31 * 8 + (size_t)hf * 256;
    float16 acc;
    #pragma unroll
    for (int q = 0; q < 16; ++q) acc[q] = 0.f;
    score_chunk(ph, pm, pl, cbase, Ah, Am, Al, acc);
    float sqv = sqb[m0 + l31];
    #pragma unroll
    for (int r = 0; r < 16; ++r) {
      float cand = __builtin_fmaf(-2.f, acc[r], sqv);
      int nrow = n0 + (r & 3) + 8 * (r >> 2) + 4 * hf;
      bool ok = (m0 + l31 != nrow) && (cand <= tau[r]);
      unsigned long long bal = __ballot(ok);
      unsigned mh = hf ? (unsigned)(bal >> 32) : (unsigned)bal;
      if (mh) {
        int pre = __popc(mh & ((1u << l31) - 1u));
        int slot = cnt[r] + pre;
        if (ok && slot < CAP) {
          unsigned bits = __float_as_uint(cand);
          unsigned key32 = bits ^ ((bits >> 31) ? 0xFFFFFFFFu : 0x80000000u);
          buf[wv][r + 16 * hf][slot] = ((u64)key32 << 32) | (unsigned)(m0 + l31);
        }
        cnt[r] += __popc(mh);
      }
    }
  }

  // -------- final: sort survivors per row/slice, emit sorted top-20 --------
  #pragma unroll
  for (int r = 0; r < 16; ++r) {
    int c = cnt[r] < CAP ? cnt[r] : CAP;
    int rr = r + 16 * hf;
    u64 k0 = (2 * l31     < c) ? buf[wv][rr][2 * l31]     : ~0ull;
    u64 k1 = (2 * l31 + 1 < c) ? buf[wv][rr][2 * l31 + 1] : ~0ull;
    bitonic64k(k0, k1, l31);
    u64 a = __shfl(k0, l31 >> 1, 32);
    u64 b2 = __shfl(k1, l31 >> 1, 32);
    u64 kv = (l31 & 1) ? b2 : a;                  // element l31 of sorted order
    if (l31 < KK) {
      int nrow = n0 + (r & 3) + 8 * (r >> 2) + 4 * hf;
      size_t rowg = ((size_t)b * NN + nrow) * SS + slice;
      keys2[rowg * KK + l31] = kv;
    }
  }
}

// ---------------- merge four sorted 20-key lists per row ----------------
__global__ void __launch_bounds__(256) merge_kernel(
    const u64* __restrict__ keys2, int* __restrict__ idxOut)
{
  int row = blockIdx.x * 256 + threadIdx.x;   // 0..32767
  if (row >= BB * NN) return;
  u64 h[SS]; int p[SS];
  #pragma unroll
  for (int s = 0; s < SS; ++s) {
    p[s] = 0;
    h[s] = keys2[((size_t)row * SS + s) * KK];
  }
  int* op = idxOut + (size_t)row * KK;
  #pragma unroll
  for (int q = 0; q < KK; ++q) {
    int bs = 0;
    u64 bv = h[0];
    #pragma unroll
    for (int s = 1; s < SS; ++s) { if (h[s] < bv) { bv = h[s]; bs = s; } }
    op[q] = (int)(unsigned)(bv & 0xFFFFFFFFull);
    p[bs]++;
    h[bs] = (p[bs] < KK) ? keys2[((size_t)row * SS + bs) * KK + p[bs]] : ~0ull;
  }
}

// ---------------- gather: out[b,o,n] = P + max_j Q[nbr_j] ----------------
__global__ void __launch_bounds__(256) gather_kernel(
    const float* __restrict__ x, const float* __restrict__ W,
    const float* __restrict__ bias,
    const float* __restrict__ Q, const int* __restrict__ idxIn,
    float* __restrict__ out)
{
  __shared__ float xs[64][65];
  __shared__ float wp[64][65];
  __shared__ float ot[64][65];
  __shared__ float bs[64];
  int t = threadIdx.x;
  int b = blockIdx.x >> 6;
  int n0 = (blockIdx.x & 63) << 6;
  const float* xb = x + (size_t)b * FF * NN;

  int nl0 = t & 63, fq = t >> 6;
  #pragma unroll
  for (int i = 0; i < 16; ++i) {
    int f = fq + i * 4;
    xs[f][nl0] = xb[(size_t)f * NN + n0 + nl0];
  }
  #pragma unroll
  for (int i = 0; i < 16; ++i) {
    int id = i * 256 + t;            // 0..4095
    int o = id >> 6, f = id & 63;
    wp[o][f] = W[o * 128 + f] - W[o * 128 + 64 + f];   // W1 - W2
  }
  if (t < 64) bs[t] = bias[t];
  __syncthreads();

  int o = t & 63, g = t >> 6;
  for (int i = 0; i < 16; ++i) {
    int nl = g + i * 4;
    int n = n0 + nl;
    float p = bs[o];
    #pragma unroll
    for (int f = 0; f < FF; ++f) p += wp[o][f] * xs[f][nl];
    const int* ip = idxIn + ((size_t)b * NN + n) * KK;
    float m = -FLT_MAX;
    #pragma unroll
    for (int j = 0; j < KK; ++j) {
      int nb = ip[j];                                   // wave-uniform
      m = fmaxf(m, Q[((size_t)b * NN + nb) * FF + o]);  // 256B coalesced
    }
    ot[nl][o] = p + m;
  }
  __syncthreads();
  for (int i = 0; i < 16; ++i) {
    int o2 = g + i * 4;
    int nl = t & 63;
    out[((size_t)b * FF + o2) * NN + n0 + nl] = ot[nl][o2];
  }
}

extern "C" void kernel_launch(void* const* d_in, const int* in_sizes, int n_in,
                              void* d_out, int out_size, void* d_ws, size_t ws_size,
                              hipStream_t stream)
{
  const float* x    = (const float*)d_in[0];
  const float* W    = (const float*)d_in[1];
  const float* bias = (const float*)d_in[2];
  float* out = (float*)d_out;

  int*   idxb = (int*)d_ws;                               // 8*4096*20
  float* sq   = (float*)(idxb + (size_t)BB * NN * KK);    // 8*4096
  float* Q    = sq + (size_t)BB * NN;                     // 8*4096*64
  ushort_t* ph = (ushort_t*)(Q + (size_t)BB * NN * FF);   // 8*4096*64 each
  ushort_t* pm = ph + (size_t)BB * NN * FF;
  ushort_t* pl = pm + (size_t)BB * NN * FF;
  u64*   keys2 = (u64*)(pl + (size_t)BB * NN * FF);       // 8*4096*4*20

  prep_kernel<<<BB * (NN / 64), 256, 0, stream>>>(x, W, sq, Q, ph, pm, pl);
  knn_kernel<<<BB * 32 * SS, 256, 0, stream>>>(ph, pm, pl, sq, keys2);
  merge_kernel<<<(BB * NN + 255) / 256, 256, 0, stream>>>(keys2, idxb);
  gather_kernel<<<BB * (NN / 64), 256, 0, stream>>>(x, W, bias, Q, idxb, out);
}

// Round 12
// 380.569 us; speedup vs baseline: 1.7092x; 1.1056x over previous
//
#include <hip/hip_runtime.h>
#include <hip/hip_bf16.h>
#include <float.h>

// EdgeConv (fp32 I/O):
//   out[b,o,n] = P[b,n,o] + max_{j<20} Q[b, idx[b,n,j], o]
//   P = (W1-W2)^T x + b ; Q = W2^T x
//   knn: top-20 smallest of score[m] = sq[m] - 2*x_n.x_m  (m != n)
// Round 12: fp16x2 split (h + m*2^-12, m stored pre-scaled by 4096 to stay
// normal) -> 3 plane-passes, 12 MFMA + 8 loads per chunk (was 24+12), fp32-
// equivalent scores (residual ~2^-24). acc1 = hh, acc2 = mh+hm (recombined
// cand = sq - 2*(acc1 + acc2*2^-12)). Plain launch_bounds(256): no forced
// AGPR spill (r11: VGPR=72 + huge AGPR block = 2 waves/SIMD + accvgpr churn).
// CAP 40 (validated r10), LDS 40960. Grid: 4 slices x 32 groups x 8 batches.

#define BB 8
#define FF 64
#define NN 4096
#define KK 20
#define CAP 40
#define SS 4

typedef unsigned short ushort_t;
typedef unsigned long long u64;
typedef __attribute__((ext_vector_type(8))) _Float16 half8;
typedef __attribute__((ext_vector_type(16))) float float16;

// plane flat index (shorts): [b][n>>5][k>>3][n&31][k&7]
__device__ __forceinline__ size_t plidx(int b, int n, int k) {
  return ((size_t)b * 128 + (n >> 5)) * 2048 + (size_t)(k >> 3) * 256 + (size_t)(n & 31) * 8 + (k & 7);
}

// ---------------- prep: sq, Q, fp16x2 planes (fragment-tiled) ----------------
__global__ void __launch_bounds__(256) prep_kernel(
    const float* __restrict__ x, const float* __restrict__ W,
    float* __restrict__ sq, float* __restrict__ Q,
    ushort_t* __restrict__ ph, ushort_t* __restrict__ pm)
{
  __shared__ float xs[64][65];
  __shared__ float w2[64][65];
  int t = threadIdx.x;
  int b = blockIdx.x >> 6;
  int n0 = (blockIdx.x & 63) << 6;
  const float* xb = x + (size_t)b * FF * NN;

  int nl = t & 63, fq = t >> 6;
  #pragma unroll
  for (int i = 0; i < 16; ++i) {
    int f = fq + i * 4;
    xs[f][nl] = xb[(size_t)f * NN + n0 + nl];
  }
  #pragma unroll
  for (int i = 0; i < 16; ++i) {
    int id = i * 256 + t;            // 0..4095
    int o = id >> 6, f = id & 63;
    w2[o][f] = W[o * 128 + 64 + f];  // W2
  }
  __syncthreads();

  if (t < 64) {
    float s = 0.f;
    #pragma unroll
    for (int f = 0; f < FF; ++f) { float v = xs[f][t]; s += v * v; }
    sq[b * NN + n0 + t] = s;
  }
  int o = t & 63, g = t >> 6;
  for (int i = 0; i < 16; ++i) {
    int r = g + i * 4;
    int n = n0 + r;
    float acc = 0.f;
    #pragma unroll
    for (int f = 0; f < FF; ++f) acc += w2[o][f] * xs[f][r];
    Q[((size_t)b * NN + n) * FF + o] = acc;

    // fp16x2 split of x[k=o][n]: x = h + m*2^-12 (m stored pre-scaled)
    float v = xs[o][r];
    _Float16 hh = (_Float16)v;
    float hf = (float)hh;
    _Float16 mm = (_Float16)((v - hf) * 4096.0f);
    size_t pb = plidx(b, n, o);
    ph[pb] = __builtin_bit_cast(unsigned short, hh);
    pm[pb] = __builtin_bit_cast(unsigned short, mm);
  }
}

// 12-MFMA score chunk (bitwise identical in both passes):
//   acc1 += Ah*Bh ; acc2 += Am*Bh + Ah*Bm
__device__ __forceinline__ void score_chunk(
    const ushort_t* __restrict__ ph, const ushort_t* __restrict__ pm,
    size_t cbase, const half8* Ah, const half8* Am,
    float16& acc1, float16& acc2)
{
  half8 Bh[4], Bm[4];
  #pragma unroll
  for (int s = 0; s < 4; ++s) Bh[s] = *(const half8*)(ph + cbase + s * 512);
  #pragma unroll
  for (int s = 0; s < 4; ++s) Bm[s] = *(const half8*)(pm + cbase + s * 512);
  #pragma unroll
  for (int s = 0; s < 4; ++s) acc1 = __builtin_amdgcn_mfma_f32_32x32x16_f16(Ah[s], Bh[s], acc1, 0, 0, 0);
  #pragma unroll
  for (int s = 0; s < 4; ++s) acc2 = __builtin_amdgcn_mfma_f32_32x32x16_f16(Am[s], Bh[s], acc2, 0, 0, 0);
  #pragma unroll
  for (int s = 0; s < 4; ++s) acc2 = __builtin_amdgcn_mfma_f32_32x32x16_f16(Ah[s], Bm[s], acc2, 0, 0, 0);
}

// ascending bitonic sort of 64 floats as elements (2l, 2l+1) across 32 lanes
__device__ __forceinline__ void bitonic64f(float& v0, float& v1, int l31)
{
  #pragma unroll
  for (int k = 2; k <= 64; k <<= 1) {
    #pragma unroll
    for (int j = k >> 1; j >= 1; j >>= 1) {
      bool dirup = ((2 * l31) & k) == 0;
      if (j >= 2) {
        int lj = j >> 1;
        float p0 = __shfl_xor(v0, lj, 32);
        float p1 = __shfl_xor(v1, lj, 32);
        bool lower = (l31 & lj) == 0;
        bool keepmin = (dirup == lower);
        v0 = keepmin ? fminf(v0, p0) : fmaxf(v0, p0);
        v1 = keepmin ? fminf(v1, p1) : fmaxf(v1, p1);
      } else {
        float lo = fminf(v0, v1), hi = fmaxf(v0, v1);
        v0 = dirup ? lo : hi;
        v1 = dirup ? hi : lo;
      }
    }
  }
}

// same network on u64 keys
__device__ __forceinline__ void bitonic64k(u64& v0, u64& v1, int l31)
{
  #pragma unroll
  for (int k = 2; k <= 64; k <<= 1) {
    #pragma unroll
    for (int j = k >> 1; j >= 1; j >>= 1) {
      bool dirup = ((2 * l31) & k) == 0;
      if (j >= 2) {
        int lj = j >> 1;
        u64 p0 = __shfl_xor(v0, lj, 32);
        u64 p1 = __shfl_xor(v1, lj, 32);
        bool lower = (l31 & lj) == 0;
        bool keepmin = (dirup == lower);
        u64 a0 = v0 < p0 ? v0 : p0, b0 = v0 < p0 ? p0 : v0;
        u64 a1 = v1 < p1 ? v1 : p1, b1 = v1 < p1 ? p1 : v1;
        v0 = keepmin ? a0 : b0;
        v1 = keepmin ? a1 : b1;
      } else {
        u64 lo = v0 < v1 ? v0 : v1, hi = v0 < v1 ? v1 : v0;
        v0 = dirup ? lo : hi;
        v1 = dirup ? hi : lo;
      }
    }
  }
}

// ---------------- knn: two-pass threshold filter, slice = 1024 cols = 32 chunks ----------------
__global__ void __launch_bounds__(256) knn_kernel(
    const ushort_t* __restrict__ ph, const ushort_t* __restrict__ pm,
    const float* __restrict__ sq, u64* __restrict__ keys2)
{
  __shared__ u64 buf[4][32][CAP];   // 40960 B

  const int t = threadIdx.x;
  const int lane = t & 63;
  const int l31 = lane & 31;
  const int hf = lane >> 5;
  const int wv = t >> 6;
  const int blk = blockIdx.x;
  const int slice = blk & 3;
  const int g = (blk >> 2) & 31;
  const int b = blk >> 7;
  const int n0 = (g * 4 + wv) * 32;

  const float* __restrict__ sqb = sq + (size_t)b * NN;
  const float MS = 2.44140625e-4f;   // 2^-12

  // resident A fragments: row = n0 + l31, k = 16*s + 8*hf + e
  half8 Ah[4], Am[4];
  {
    size_t abase = ((size_t)b * 128 + (n0 >> 5)) * 2048 + (size_t)l31 * 8 + (size_t)hf * 256;
    #pragma unroll
    for (int s = 0; s < 4; ++s) {
      Ah[s] = *(const half8*)(ph + abase + s * 512);
      Am[s] = *(const half8*)(pm + abase + s * 512);
    }
  }

  // -------- pass A: per-lane min2 per row over 32 chunks --------
  float m1[16], m2[16];
  #pragma unroll
  for (int r = 0; r < 16; ++r) { m1[r] = FLT_MAX; m2[r] = FLT_MAX; }

  for (int mc = 0; mc < 32; ++mc) {
    const int m0 = slice * 1024 + mc * 32;
    size_t cbase = ((size_t)b * 128 + (m0 >> 5)) * 2048 + (size_t)l31 * 8 + (size_t)hf * 256;
    float16 acc1, acc2;
    #pragma unroll
    for (int q = 0; q < 16; ++q) { acc1[q] = 0.f; acc2[q] = 0.f; }
    score_chunk(ph, pm, cbase, Ah, Am, acc1, acc2);
    float sqv = sqb[m0 + l31];
    #pragma unroll
    for (int r = 0; r < 16; ++r) {
      float dot = __builtin_fmaf(acc2[r], MS, acc1[r]);
      float cand = __builtin_fmaf(-2.f, dot, sqv);
      int nrow = n0 + (r & 3) + 8 * (r >> 2) + 4 * hf;
      if (m0 + l31 == nrow) cand = FLT_MAX;       // self-exclusion
      m2[r] = fminf(m2[r], fmaxf(cand, m1[r]));
      m1[r] = fminf(m1[r], cand);
    }
  }

  // tau_r = 20th smallest (0-based 19) of the 64-pool of per-lane min2
  float tau[16];
  #pragma unroll
  for (int r = 0; r < 16; ++r) {
    float v0 = m1[r], v1 = m2[r];
    bitonic64f(v0, v1, l31);
    tau[r] = __shfl(v1, 9, 32);                   // element 19 = lane 9, reg 1
  }

  // -------- pass B: recompute, compact survivors into LDS --------
  int cnt[16];
  #pragma unroll
  for (int r = 0; r < 16; ++r) cnt[r] = 0;

  for (int mc = 0; mc < 32; ++mc) {
    const int m0 = slice * 1024 + mc * 32;
    size_t cbase = ((size_t)b * 128 + (m0 >> 5)) * 2048 + (size_t)l31 * 8 + (size_t)hf * 256;
    float16 acc1, acc2;
    #pragma unroll
    for (int q = 0; q < 16; ++q) { acc1[q] = 0.f; acc2[q] = 0.f; }
    score_chunk(ph, pm, cbase, Ah, Am, acc1, acc2);
    float sqv = sqb[m0 + l31];
    #pragma unroll
    for (int r = 0; r < 16; ++r) {
      float dot = __builtin_fmaf(acc2[r], MS, acc1[r]);
      float cand = __builtin_fmaf(-2.f, dot, sqv);
      int nrow = n0 + (r & 3) + 8 * (r >> 2) + 4 * hf;
      bool ok = (m0 + l31 != nrow) && (cand <= tau[r]);
      unsigned long long bal = __ballot(ok);
      unsigned mh = hf ? (unsigned)(bal >> 32) : (unsigned)bal;
      if (mh) {
        int pre = __popc(mh & ((1u << l31) - 1u));
        int slot = cnt[r] + pre;
        if (ok && slot < CAP) {
          unsigned bits = __float_as_uint(cand);
          unsigned key32 = bits ^ ((bits >> 31) ? 0xFFFFFFFFu : 0x80000000u);
          buf[wv][r + 16 * hf][slot] = ((u64)key32 << 32) | (unsigned)(m0 + l31);
        }
        cnt[r] += __popc(mh);
      }
    }
  }

  // -------- final: sort survivors per row/slice, emit sorted top-20 --------
  #pragma unroll
  for (int r = 0; r < 16; ++r) {
    int c = cnt[r] < CAP ? cnt[r] : CAP;
    int rr = r + 16 * hf;
    u64 k0 = (2 * l31     < c) ? buf[wv][rr][2 * l31]     : ~0ull;
    u64 k1 = (2 * l31 + 1 < c) ? buf[wv][rr][2 * l31 + 1] : ~0ull;
    bitonic64k(k0, k1, l31);
    u64 a = __shfl(k0, l31 >> 1, 32);
    u64 b2 = __shfl(k1, l31 >> 1, 32);
    u64 kv = (l31 & 1) ? b2 : a;                  // element l31 of sorted order
    if (l31 < KK) {
      int nrow = n0 + (r & 3) + 8 * (r >> 2) + 4 * hf;
      size_t rowg = ((size_t)b * NN + nrow) * SS + slice;
      keys2[rowg * KK + l31] = kv;
    }
  }
}

// ---------------- merge four sorted 20-key lists per row ----------------
__global__ void __launch_bounds__(256) merge_kernel(
    const u64* __restrict__ keys2, int* __restrict__ idxOut)
{
  int row = blockIdx.x * 256 + threadIdx.x;   // 0..32767
  if (row >= BB * NN) return;
  u64 h[SS]; int p[SS];
  #pragma unroll
  for (int s = 0; s < SS; ++s) {
    p[s] = 0;
    h[s] = keys2[((size_t)row * SS + s) * KK];
  }
  int* op = idxOut + (size_t)row * KK;
  #pragma unroll
  for (int q = 0; q < KK; ++q) {
    int bs = 0;
    u64 bv = h[0];
    #pragma unroll
    for (int s = 1; s < SS; ++s) { if (h[s] < bv) { bv = h[s]; bs = s; } }
    op[q] = (int)(unsigned)(bv & 0xFFFFFFFFull);
    p[bs]++;
    h[bs] = (p[bs] < KK) ? keys2[((size_t)row * SS + bs) * KK + p[bs]] : ~0ull;
  }
}

// ---------------- gather: out[b,o,n] = P + max_j Q[nbr_j] ----------------
__global__ void __launch_bounds__(256) gather_kernel(
    const float* __restrict__ x, const float* __restrict__ W,
    const float* __restrict__ bias,
    const float* __restrict__ Q, const int* __restrict__ idxIn,
    float* __restrict__ out)
{
  __shared__ float xs[64][65];
  __shared__ float wp[64][65];
  __shared__ float ot[64][65];
  __shared__ float bs[64];
  int t = threadIdx.x;
  int b = blockIdx.x >> 6;
  int n0 = (blockIdx.x & 63) << 6;
  const float* xb = x + (size_t)b * FF * NN;

  int nl0 = t & 63, fq = t >> 6;
  #pragma unroll
  for (int i = 0; i < 16; ++i) {
    int f = fq + i * 4;
    xs[f][nl0] = xb[(size_t)f * NN + n0 + nl0];
  }
  #pragma unroll
  for (int i = 0; i < 16; ++i) {
    int id = i * 256 + t;            // 0..4095
    int o = id >> 6, f = id & 63;
    wp[o][f] = W[o * 128 + f] - W[o * 128 + 64 + f];   // W1 - W2
  }
  if (t < 64) bs[t] = bias[t];
  __syncthreads();

  int o = t & 63, g = t >> 6;
  for (int i = 0; i < 16; ++i) {
    int nl = g + i * 4;
    int n = n0 + nl;
    float p = bs[o];
    #pragma unroll
    for (int f = 0; f < FF; ++f) p += wp[o][f] * xs[f][nl];
    const int* ip = idxIn + ((size_t)b * NN + n) * KK;
    float m = -FLT_MAX;
    #pragma unroll
    for (int j = 0; j < KK; ++j) {
      int nb = ip[j];                                   // wave-uniform
      m = fmaxf(m, Q[((size_t)b * NN + nb) * FF + o]);  // 256B coalesced
    }
    ot[nl][o] = p + m;
  }
  __syncthreads();
  for (int i = 0; i < 16; ++i) {
    int o2 = g + i * 4;
    int nl = t & 63;
    out[((size_t)b * FF + o2) * NN + n0 + nl] = ot[nl][o2];
  }
}

extern "C" void kernel_launch(void* const* d_in, const int* in_sizes, int n_in,
                              void* d_out, int out_size, void* d_ws, size_t ws_size,
                              hipStream_t stream)
{
  const float* x    = (const float*)d_in[0];
  const float* W    = (const float*)d_in[1];
  const float* bias = (const float*)d_in[2];
  float* out = (float*)d_out;

  int*   idxb = (int*)d_ws;                               // 8*4096*20
  float* sq   = (float*)(idxb + (size_t)BB * NN * KK);    // 8*4096
  float* Q    = sq + (size_t)BB * NN;                     // 8*4096*64
  ushort_t* ph = (ushort_t*)(Q + (size_t)BB * NN * FF);   // 8*4096*64 each
  ushort_t* pm = ph + (size_t)BB * NN * FF;
  u64*   keys2 = (u64*)(pm + (size_t)BB * NN * FF);       // 8*4096*4*20

  prep_kernel<<<BB * (NN / 64), 256, 0, stream>>>(x, W, sq, Q, ph, pm);
  knn_kernel<<<BB * 32 * SS, 256, 0, stream>>>(ph, pm, sq, keys2);
  merge_kernel<<<(BB * NN + 255) / 256, 256, 0, stream>>>(keys2, idxb);
  gather_kernel<<<BB * (NN / 64), 256, 0, stream>>>(x, W, bias, Q, idxb, out);
}

// Round 14
// 326.131 us; speedup vs baseline: 1.9945x; 1.1669x over previous
//
#include <hip/hip_runtime.h>
#include <hip/hip_bf16.h>
#include <float.h>

// EdgeConv (fp32 I/O):
//   out[b,o,n] = P[b,n,o] + max_{j<20} Q[b, idx[b,n,j], o]
//   P = (W1-W2)^T x + b ; Q = W2^T x
//   knn: top-20 smallest of score[m] = sq[m] - 2*x_n.x_m  (m != n)
// Round 14: round 13 with the grid-coverage bug fixed (64 groups/batch, not
// 32 -- 16-row waves halved tile size so the grid must double; r13 left rows
// 2048+ unwritten -> poisoned keys2 -> OOB gather -> abort).
// knn on 16x16x32 f16 MFMA, one 16-row tile/wave, per-lane live state ~90
// VGPRs (no AGPR churn). fp16x2 split scores (fp32-equivalent).
// tau = 20th of 32-pool. CAP 64. Planes tiled [b][n>>4][k>>3][n&15][k&7].

#define BB 8
#define FF 64
#define NN 4096
#define KK 20
#define CAP 64
#define SS 4

typedef unsigned short ushort_t;
typedef unsigned long long u64;
typedef __attribute__((ext_vector_type(8))) _Float16 half8;
typedef __attribute__((ext_vector_type(4))) float floatx4;

// plane flat index (shorts): [b][n>>4][k>>3][n&15][k&7]
__device__ __forceinline__ size_t plidx16(int b, int n, int k) {
  return ((size_t)b * 256 + (n >> 4)) * 1024 + (size_t)(k >> 3) * 128 + (size_t)(n & 15) * 8 + (k & 7);
}

// ---------------- prep: sq, Q, fp16x2 planes (16-point fragment tiles) ----------------
__global__ void __launch_bounds__(256) prep_kernel(
    const float* __restrict__ x, const float* __restrict__ W,
    float* __restrict__ sq, float* __restrict__ Q,
    ushort_t* __restrict__ ph, ushort_t* __restrict__ pm)
{
  __shared__ float xs[64][65];
  __shared__ float w2[64][65];
  int t = threadIdx.x;
  int b = blockIdx.x >> 6;
  int n0 = (blockIdx.x & 63) << 6;
  const float* xb = x + (size_t)b * FF * NN;

  int nl = t & 63, fq = t >> 6;
  #pragma unroll
  for (int i = 0; i < 16; ++i) {
    int f = fq + i * 4;
    xs[f][nl] = xb[(size_t)f * NN + n0 + nl];
  }
  #pragma unroll
  for (int i = 0; i < 16; ++i) {
    int id = i * 256 + t;            // 0..4095
    int o = id >> 6, f = id & 63;
    w2[o][f] = W[o * 128 + 64 + f];  // W2
  }
  __syncthreads();

  if (t < 64) {
    float s = 0.f;
    #pragma unroll
    for (int f = 0; f < FF; ++f) { float v = xs[f][t]; s += v * v; }
    sq[b * NN + n0 + t] = s;
  }
  int o = t & 63, g = t >> 6;
  for (int i = 0; i < 16; ++i) {
    int r = g + i * 4;
    int n = n0 + r;
    float acc = 0.f;
    #pragma unroll
    for (int f = 0; f < FF; ++f) acc += w2[o][f] * xs[f][r];
    Q[((size_t)b * NN + n) * FF + o] = acc;

    // fp16x2 split: x = h + m*2^-12 (m stored pre-scaled by 4096)
    float v = xs[o][r];
    _Float16 hh = (_Float16)v;
    float hf = (float)hh;
    _Float16 mm = (_Float16)((v - hf) * 4096.0f);
    size_t pb = plidx16(b, n, o);
    ph[pb] = __builtin_bit_cast(unsigned short, hh);
    pm[pb] = __builtin_bit_cast(unsigned short, mm);
  }
}

// ascending bitonic sort of 32 floats as elements (2l, 2l+1) across 16 lanes
__device__ __forceinline__ void bitonic32f(float& v0, float& v1, int l15)
{
  #pragma unroll
  for (int k = 2; k <= 32; k <<= 1) {
    #pragma unroll
    for (int j = k >> 1; j >= 1; j >>= 1) {
      bool dirup = ((2 * l15) & k) == 0;
      if (j >= 2) {
        int lj = j >> 1;
        float p0 = __shfl_xor(v0, lj, 16);
        float p1 = __shfl_xor(v1, lj, 16);
        bool lower = (l15 & lj) == 0;
        bool keepmin = (dirup == lower);
        v0 = keepmin ? fminf(v0, p0) : fmaxf(v0, p0);
        v1 = keepmin ? fminf(v1, p1) : fmaxf(v1, p1);
      } else {
        float lo = fminf(v0, v1), hi = fmaxf(v0, v1);
        v0 = dirup ? lo : hi;
        v1 = dirup ? hi : lo;
      }
    }
  }
}

// ascending bitonic sort of 64 u64 keys as elements (2l, 2l+1) across 32 lanes
__device__ __forceinline__ void bitonic64k(u64& v0, u64& v1, int l31)
{
  #pragma unroll
  for (int k = 2; k <= 64; k <<= 1) {
    #pragma unroll
    for (int j = k >> 1; j >= 1; j >>= 1) {
      bool dirup = ((2 * l31) & k) == 0;
      if (j >= 2) {
        int lj = j >> 1;
        u64 p0 = __shfl_xor(v0, lj, 32);
        u64 p1 = __shfl_xor(v1, lj, 32);
        bool lower = (l31 & lj) == 0;
        bool keepmin = (dirup == lower);
        u64 a0 = v0 < p0 ? v0 : p0, b0 = v0 < p0 ? p0 : v0;
        u64 a1 = v1 < p1 ? v1 : p1, b1 = v1 < p1 ? p1 : v1;
        v0 = keepmin ? a0 : b0;
        v1 = keepmin ? a1 : b1;
      } else {
        u64 lo = v0 < v1 ? v0 : v1, hi = v0 < v1 ? v1 : v0;
        v0 = dirup ? lo : hi;
        v1 = dirup ? hi : lo;
      }
    }
  }
}

// ---------------- knn: two-pass threshold filter, 16 rows/wave ----------------
__global__ void __launch_bounds__(256) knn_kernel(
    const ushort_t* __restrict__ ph, const ushort_t* __restrict__ pm,
    const float* __restrict__ sq, u64* __restrict__ keys2)
{
  __shared__ u64 buf[4][16][CAP];   // 32768 B
  __shared__ int scnt[4][16];

  const int t = threadIdx.x;
  const int lane = t & 63;
  const int l15 = lane & 15;
  const int q = lane >> 4;          // quarter 0..3 (C rows 4q..4q+3)
  const int wv = t >> 6;
  const int blk = blockIdx.x;
  const int slice = blk & 3;
  const int g = (blk >> 2) & 63;    // 64 groups per batch (FIXED: was &31)
  const int b = blk >> 8;
  const int n0w = (g * 4 + wv) * 16;   // this wave's 16-row tile

  const float* __restrict__ sqb = sq + (size_t)b * NN;
  const float MS = 2.44140625e-4f;   // 2^-12
  const int laneoff = q * 128 + l15 * 8;

  // resident A fragments: row = l15, k = 32s + 8q + e
  half8 Ah[2], Am[2];
  {
    size_t abase = ((size_t)b * 256 + (n0w >> 4)) * 1024 + laneoff;
    #pragma unroll
    for (int s = 0; s < 2; ++s) {
      Ah[s] = *(const half8*)(ph + abase + s * 512);
      Am[s] = *(const half8*)(pm + abase + s * 512);
    }
  }

  // -------- pass A: per-lane min2 per row over 32 chunks (2 cands/row/chunk) --------
  float m1[4], m2[4];
  #pragma unroll
  for (int r = 0; r < 4; ++r) { m1[r] = FLT_MAX; m2[r] = FLT_MAX; }

  for (int mc = 0; mc < 32; ++mc) {
    const int m0 = slice * 1024 + mc * 32;
    size_t mbase = ((size_t)b * 256 + (m0 >> 4)) * 1024 + laneoff;
    floatx4 a1[2], a2[2];
    #pragma unroll
    for (int ti = 0; ti < 2; ++ti)
      #pragma unroll
      for (int e = 0; e < 4; ++e) { a1[ti][e] = 0.f; a2[ti][e] = 0.f; }
    #pragma unroll
    for (int ti = 0; ti < 2; ++ti) {
      #pragma unroll
      for (int s = 0; s < 2; ++s) {
        half8 Bh = *(const half8*)(ph + mbase + ti * 1024 + s * 512);
        half8 Bm = *(const half8*)(pm + mbase + ti * 1024 + s * 512);
        a1[ti] = __builtin_amdgcn_mfma_f32_16x16x32_f16(Ah[s], Bh, a1[ti], 0, 0, 0);
        a2[ti] = __builtin_amdgcn_mfma_f32_16x16x32_f16(Am[s], Bh, a2[ti], 0, 0, 0);
        a2[ti] = __builtin_amdgcn_mfma_f32_16x16x32_f16(Ah[s], Bm, a2[ti], 0, 0, 0);
      }
    }
    #pragma unroll
    for (int ti = 0; ti < 2; ++ti) {
      float sqv = sqb[m0 + 16 * ti + l15];
      int mcol = m0 + 16 * ti + l15;
      #pragma unroll
      for (int r = 0; r < 4; ++r) {
        float dot = __builtin_fmaf(a2[ti][r], MS, a1[ti][r]);
        float cand = __builtin_fmaf(-2.f, dot, sqv);
        int nrow = n0w + 4 * q + r;
        if (mcol == nrow) cand = FLT_MAX;      // self-exclusion
        m2[r] = fminf(m2[r], fmaxf(cand, m1[r]));
        m1[r] = fminf(m1[r], cand);
      }
    }
  }

  // tau_r = 20th smallest (0-based 19) of each row's 32-pool (16 lanes x min2)
  float tau[4];
  #pragma unroll
  for (int r = 0; r < 4; ++r) {
    float v0 = m1[r], v1 = m2[r];
    bitonic32f(v0, v1, l15);
    tau[r] = __shfl(v1, 9, 16);                // element 19 = lane 9, reg 1
  }

  // -------- pass B: recompute, compact survivors into LDS --------
  int cnt[4];
  #pragma unroll
  for (int r = 0; r < 4; ++r) cnt[r] = 0;

  for (int mc = 0; mc < 32; ++mc) {
    const int m0 = slice * 1024 + mc * 32;
    size_t mbase = ((size_t)b * 256 + (m0 >> 4)) * 1024 + laneoff;
    floatx4 a1[2], a2[2];
    #pragma unroll
    for (int ti = 0; ti < 2; ++ti)
      #pragma unroll
      for (int e = 0; e < 4; ++e) { a1[ti][e] = 0.f; a2[ti][e] = 0.f; }
    #pragma unroll
    for (int ti = 0; ti < 2; ++ti) {
      #pragma unroll
      for (int s = 0; s < 2; ++s) {
        half8 Bh = *(const half8*)(ph + mbase + ti * 1024 + s * 512);
        half8 Bm = *(const half8*)(pm + mbase + ti * 1024 + s * 512);
        a1[ti] = __builtin_amdgcn_mfma_f32_16x16x32_f16(Ah[s], Bh, a1[ti], 0, 0, 0);
        a2[ti] = __builtin_amdgcn_mfma_f32_16x16x32_f16(Am[s], Bh, a2[ti], 0, 0, 0);
        a2[ti] = __builtin_amdgcn_mfma_f32_16x16x32_f16(Ah[s], Bm, a2[ti], 0, 0, 0);
      }
    }
    #pragma unroll
    for (int ti = 0; ti < 2; ++ti) {
      float sqv = sqb[m0 + 16 * ti + l15];
      int mcol = m0 + 16 * ti + l15;
      #pragma unroll
      for (int r = 0; r < 4; ++r) {
        float dot = __builtin_fmaf(a2[ti][r], MS, a1[ti][r]);
        float cand = __builtin_fmaf(-2.f, dot, sqv);
        int nrow = n0w + 4 * q + r;
        bool ok = (mcol != nrow) && (cand <= tau[r]);
        unsigned long long bal = __ballot(ok);
        unsigned mh = (unsigned)((bal >> (q * 16)) & 0xFFFFull);
        int pre = __popc(mh & ((1u << l15) - 1u));
        int slot = cnt[r] + pre;
        if (ok && slot < CAP) {
          unsigned bits = __float_as_uint(cand);
          unsigned key32 = bits ^ ((bits >> 31) ? 0xFFFFFFFFu : 0x80000000u);
          buf[wv][4 * q + r][slot] = ((u64)key32 << 32) | (unsigned)mcol;
        }
        cnt[r] += __popc(mh);
      }
    }
  }

  if (l15 == 0) {
    #pragma unroll
    for (int r = 0; r < 4; ++r) scnt[wv][4 * q + r] = cnt[r];
  }
  __builtin_amdgcn_s_waitcnt(0);   // drain LDS writes (same-wave read below)

  // -------- final: per half-wave, sort 8 rows' survivors, emit sorted top-20 --------
  const int l31 = t & 31;
  const int hfw = (t >> 5) & 1;
  #pragma unroll
  for (int i = 0; i < 8; ++i) {
    int rloc = hfw * 8 + i;
    int c = scnt[wv][rloc];
    c = c < CAP ? c : CAP;
    u64 k0 = (2 * l31     < c) ? buf[wv][rloc][2 * l31]     : ~0ull;
    u64 k1 = (2 * l31 + 1 < c) ? buf[wv][rloc][2 * l31 + 1] : ~0ull;
    bitonic64k(k0, k1, l31);
    u64 a = __shfl(k0, l31 >> 1, 32);
    u64 b2 = __shfl(k1, l31 >> 1, 32);
    u64 kv = (l31 & 1) ? b2 : a;              // element l31 of sorted order
    if (l31 < KK) {
      size_t rowg = ((size_t)b * NN + n0w + rloc) * SS + slice;
      keys2[rowg * KK + l31] = kv;
    }
  }
}

// ---------------- merge four sorted 20-key lists per row ----------------
__global__ void __launch_bounds__(256) merge_kernel(
    const u64* __restrict__ keys2, int* __restrict__ idxOut)
{
  int row = blockIdx.x * 256 + threadIdx.x;   // 0..32767
  if (row >= BB * NN) return;
  u64 h[SS]; int p[SS];
  #pragma unroll
  for (int s = 0; s < SS; ++s) {
    p[s] = 0;
    h[s] = keys2[((size_t)row * SS + s) * KK];
  }
  int* op = idxOut + (size_t)row * KK;
  #pragma unroll
  for (int q = 0; q < KK; ++q) {
    int bs = 0;
    u64 bv = h[0];
    #pragma unroll
    for (int s = 1; s < SS; ++s) { if (h[s] < bv) { bv = h[s]; bs = s; } }
    op[q] = (int)(unsigned)(bv & 0xFFFFFFFFull);
    p[bs]++;
    h[bs] = (p[bs] < KK) ? keys2[((size_t)row * SS + bs) * KK + p[bs]] : ~0ull;
  }
}

// ---------------- gather: out[b,o,n] = P + max_j Q[nbr_j] ----------------
__global__ void __launch_bounds__(256) gather_kernel(
    const float* __restrict__ x, const float* __restrict__ W,
    const float* __restrict__ bias,
    const float* __restrict__ Q, const int* __restrict__ idxIn,
    float* __restrict__ out)
{
  __shared__ float xs[64][65];
  __shared__ float wp[64][65];
  __shared__ float ot[64][65];
  __shared__ float bs[64];
  int t = threadIdx.x;
  int b = blockIdx.x >> 6;
  int n0 = (blockIdx.x & 63) << 6;
  const float* xb = x + (size_t)b * FF * NN;

  int nl0 = t & 63, fq = t >> 6;
  #pragma unroll
  for (int i = 0; i < 16; ++i) {
    int f = fq + i * 4;
    xs[f][nl0] = xb[(size_t)f * NN + n0 + nl0];
  }
  #pragma unroll
  for (int i = 0; i < 16; ++i) {
    int id = i * 256 + t;            // 0..4095
    int o = id >> 6, f = id & 63;
    wp[o][f] = W[o * 128 + f] - W[o * 128 + 64 + f];   // W1 - W2
  }
  if (t < 64) bs[t] = bias[t];
  __syncthreads();

  int o = t & 63, g = t >> 6;
  for (int i = 0; i < 16; ++i) {
    int nl = g + i * 4;
    int n = n0 + nl;
    float p = bs[o];
    #pragma unroll
    for (int f = 0; f < FF; ++f) p += wp[o][f] * xs[f][nl];
    const int* ip = idxIn + ((size_t)b * NN + n) * KK;
    float m = -FLT_MAX;
    #pragma unroll
    for (int j = 0; j < KK; ++j) {
      int nb = ip[j];                                   // wave-uniform
      m = fmaxf(m, Q[((size_t)b * NN + nb) * FF + o]);  // 256B coalesced
    }
    ot[nl][o] = p + m;
  }
  __syncthreads();
  for (int i = 0; i < 16; ++i) {
    int o2 = g + i * 4;
    int nl = t & 63;
    out[((size_t)b * FF + o2) * NN + n0 + nl] = ot[nl][o2];
  }
}

extern "C" void kernel_launch(void* const* d_in, const int* in_sizes, int n_in,
                              void* d_out, int out_size, void* d_ws, size_t ws_size,
                              hipStream_t stream)
{
  const float* x    = (const float*)d_in[0];
  const float* W    = (const float*)d_in[1];
  const float* bias = (const float*)d_in[2];
  float* out = (float*)d_out;

  int*   idxb = (int*)d_ws;                               // 8*4096*20
  float* sq   = (float*)(idxb + (size_t)BB * NN * KK);    // 8*4096
  float* Q    = sq + (size_t)BB * NN;                     // 8*4096*64
  ushort_t* ph = (ushort_t*)(Q + (size_t)BB * NN * FF);   // 8*4096*64 each
  ushort_t* pm = ph + (size_t)BB * NN * FF;
  u64*   keys2 = (u64*)(pm + (size_t)BB * NN * FF);       // 8*4096*4*20

  prep_kernel<<<BB * (NN / 64), 256, 0, stream>>>(x, W, sq, Q, ph, pm);
  knn_kernel<<<BB * 64 * SS, 256, 0, stream>>>(ph, pm, sq, keys2);   // 2048 blocks
  merge_kernel<<<(BB * NN + 255) / 256, 256, 0, stream>>>(keys2, idxb);
  gather_kernel<<<BB * (NN / 64), 256, 0, stream>>>(x, W, bias, Q, idxb, out);
}